// Round 4
// baseline (570.021 us; speedup 1.0000x reference)
//
#include <hip/hip_runtime.h>

// BootstrapEnsemble: M=100 MLPs (16 -> 128 -> 4x(128x128) -> {mu, log sigma}),
// shared batch N=16384.
//  1) cvt_weights: one-shot fp32->bf16 (linear, row-major) of x/W1/Wh/Wmu/Wsig
//     into d_ws.
//  2) ens_mlp: fused MFMA MLP. Block = (model, 128-row n-chunk), 4 waves 2x2.
//     LDS = 32 KB h tile only -> 4 blocks/CU (50% occupancy) with VGPR<=128
//     via __launch_bounds__(256,4). W fragments stream from L2-hot global
//     per-kc (16 VGPR live). Swapped-operand mfma_16x16x32_bf16; bias rides
//     in the MFMA C operand. LDS XOR swizzle: col ^= (row&15)<<3.

typedef float  f32x4  __attribute__((ext_vector_type(4)));
typedef __bf16 bf16x4 __attribute__((ext_vector_type(4)));
typedef __bf16 bf16x8 __attribute__((ext_vector_type(8)));

union BF8 { bf16x8 v; unsigned int ui[4]; };
union BF4 { bf16x4 v; uint2 u2; };

#define MODELS 100
#define NPT    16384
#define HDIM   128
#define SG_OFF (MODELS * NPT)

// d_ws layout (bf16 element offsets), all row-major / linear
#define XB_OFF   0                       // x:    16384 x 16
#define W1B_OFF  262144                  // W1:   100 x 128 x 16
#define WHB_OFF  466944                  // Wh:   100 x 4 x 128 x 128
#define WMU_OFF  7020544                 // Wmu:  100 x 128
#define WSG_OFF  7033344                 // Wsig: 100 x 128

#define GTOT 880768                      // total 8-elem groups

__global__ __launch_bounds__(256) void cvt_weights(
    const float* __restrict__ x,   const float* __restrict__ W1,
    const float* __restrict__ Wh,  const float* __restrict__ Wmu,
    const float* __restrict__ Wsg, unsigned short* __restrict__ ws)
{
  int gid = blockIdx.x * 256 + threadIdx.x;
  if (gid >= GTOT) return;
  const float* src;
  unsigned int dst;
  if (gid < 32768)       { src = x   + gid * 8;                 dst = XB_OFF  + gid * 8; }
  else if (gid < 58368)  { int q = gid - 32768;  src = W1  + q * 8;          dst = W1B_OFF + q * 8; }
  else if (gid < 877568) { int q = gid - 58368;  src = Wh  + (size_t)q * 8;  dst = WHB_OFF + q * 8; }
  else if (gid < 879168) { int q = gid - 877568; src = Wmu + q * 8;          dst = WMU_OFF + q * 8; }
  else                   { int q = gid - 879168; src = Wsg + q * 8;          dst = WSG_OFF + q * 8; }
  f32x4 a = *(const f32x4*)src;
  f32x4 b = *(const f32x4*)(src + 4);
  BF4 lo, hi;
  lo.v = __builtin_convertvector(a, bf16x4);
  hi.v = __builtin_convertvector(b, bf16x4);
  uint4 u; u.x = lo.u2.x; u.y = lo.u2.y; u.z = hi.u2.x; u.w = hi.u2.y;
  *(uint4*)&ws[dst] = u;
}

__global__ __launch_bounds__(256, 4) void ens_mlp(
    const unsigned short* __restrict__ ws,
    const float* __restrict__ b1,  const float* __restrict__ bh,
    const float* __restrict__ bmu, const float* __restrict__ bsg,
    float* __restrict__ out)
{
  __shared__ unsigned short hbuf[HDIM * HDIM]; // [n 0..127][h 0..127] bf16, swizzled

  // XCD-chunked bijective swizzle: 12800 blocks = 8 XCDs * 1600
  const int bid = blockIdx.x;
  const int swz = (bid & 7) * 1600 + (bid >> 3);
  const int m   = swz >> 7;            // model 0..99
  const int n0  = (swz & 127) << 7;    // 128-row chunk base

  const int t    = threadIdx.x;
  const int lane = t & 63;
  const int wv   = t >> 6;     // wave 0..3
  const int wk   = wv & 1;     // k_out half
  const int wn   = wv >> 1;    // n half
  const int c    = lane & 15;  // frag row (A: k_out, B: n) / D col (n)
  const int g    = lane >> 4;  // frag k-group / D row group
  const int cs   = c << 3;     // xor swizzle ((row&15)<<3)

  const f32x4 zf = {0.0f, 0.0f, 0.0f, 0.0f};

  f32x4 acc[4][4];   // [kt][nt]

  // ---------------- layer 1 (K=16 zero-padded to 32) -----------------------
  {
    const unsigned short* W1m = ws + W1B_OFF + m * (HDIM * 16);
    const unsigned short* xbp = ws + XB_OFF;
    BF8 a1[4], xb[4];
    #pragma unroll
    for (int kt = 0; kt < 4; ++kt) {
      if (g < 2) {
        a1[kt].v = *(const bf16x8*)&W1m[(wk * 64 + kt * 16 + c) * 16 + g * 8];
      } else {
        a1[kt].ui[0] = 0u; a1[kt].ui[1] = 0u; a1[kt].ui[2] = 0u; a1[kt].ui[3] = 0u;
      }
    }
    #pragma unroll
    for (int nt = 0; nt < 4; ++nt) {
      if (g < 2) {
        xb[nt].v = *(const bf16x8*)&xbp[(n0 + wn * 64 + nt * 16 + c) * 16 + g * 8];
      } else {
        xb[nt].ui[0] = 0u; xb[nt].ui[1] = 0u; xb[nt].ui[2] = 0u; xb[nt].ui[3] = 0u;
      }
    }
    f32x4 bs[4];
    #pragma unroll
    for (int kt = 0; kt < 4; ++kt)
      bs[kt] = *(const f32x4*)(b1 + m * HDIM + (wk * 4 + kt) * 16 + g * 4);

    #pragma unroll
    for (int kt = 0; kt < 4; ++kt)
      #pragma unroll
      for (int nt = 0; nt < 4; ++nt)
        acc[kt][nt] = __builtin_amdgcn_mfma_f32_16x16x32_bf16(a1[kt].v, xb[nt].v, bs[kt], 0, 0, 0);

    // epilogue: relu + cvt -> hbuf
    #pragma unroll
    for (int kt = 0; kt < 4; ++kt) {
      int col = ((wk * 4 + kt) * 16 + g * 4) ^ cs;
      #pragma unroll
      for (int nt = 0; nt < 4; ++nt) {
        int row = wn * 64 + nt * 16 + c;
        f32x4 v = __builtin_elementwise_max(acc[kt][nt], zf);
        BF4 b; b.v = __builtin_convertvector(v, bf16x4);
        *(uint2*)&hbuf[row * HDIM + col] = b.u2;
      }
    }
  }
  __syncthreads();

  // ---------------- 4 hidden layers ----------------------------------------
  for (int i = 0; i < 4; ++i) {
    const unsigned short* whm = ws + WHB_OFF + (size_t)(m * 4 + i) * (HDIM * HDIM);

    {
      f32x4 bs[4];
      #pragma unroll
      for (int kt = 0; kt < 4; ++kt)
        bs[kt] = *(const f32x4*)(bh + m * 512 + i * HDIM + (wk * 4 + kt) * 16 + g * 4);
      #pragma unroll
      for (int kt = 0; kt < 4; ++kt)
        #pragma unroll
        for (int nt = 0; nt < 4; ++nt)
          acc[kt][nt] = bs[kt];
    }

    #pragma unroll
    for (int kc = 0; kc < 4; ++kc) {
      BF8 af[4], bf[4];
      #pragma unroll
      for (int kt = 0; kt < 4; ++kt)
        af[kt].v = *(const bf16x8*)&whm[(wk * 64 + kt * 16 + c) * HDIM + kc * 32 + g * 8];
      #pragma unroll
      for (int nt = 0; nt < 4; ++nt)
        bf[nt].v = *(const bf16x8*)&hbuf[(wn * 64 + nt * 16 + c) * HDIM + ((kc * 32 + g * 8) ^ cs)];
      #pragma unroll
      for (int kt = 0; kt < 4; ++kt)
        #pragma unroll
        for (int nt = 0; nt < 4; ++nt)
          acc[kt][nt] = __builtin_amdgcn_mfma_f32_16x16x32_bf16(af[kt].v, bf[nt].v, acc[kt][nt], 0, 0, 0);
    }
    __syncthreads();   // all h reads of this layer done

    // epilogue: relu + cvt, write h in place
    #pragma unroll
    for (int kt = 0; kt < 4; ++kt) {
      int col = ((wk * 4 + kt) * 16 + g * 4) ^ cs;
      #pragma unroll
      for (int nt = 0; nt < 4; ++nt) {
        int row = wn * 64 + nt * 16 + c;
        f32x4 v = __builtin_elementwise_max(acc[kt][nt], zf);
        BF4 b; b.v = __builtin_convertvector(v, bf16x4);
        *(uint2*)&hbuf[row * HDIM + col] = b.u2;
      }
    }
    __syncthreads();
  }

  // ---------------- heads: mu (row 0) and log-sigma (row 1) ----------------
  {
    float bm  = bmu[m];
    float bsv = bsg[m];
    f32x4 acc2[2];
    #pragma unroll
    for (int nt = 0; nt < 2; ++nt) {
      acc2[nt] = zf;
      acc2[nt][0] = bm;
      acc2[nt][1] = bsv;
    }
    #pragma unroll
    for (int kc = 0; kc < 4; ++kc) {
      BF8 hw;
      if (c < 2) {
        const unsigned short* wp = ws + (c == 0 ? WMU_OFF : WSG_OFF) + m * HDIM + kc * 32 + g * 8;
        hw.v = *(const bf16x8*)wp;
      } else {
        hw.ui[0] = 0u; hw.ui[1] = 0u; hw.ui[2] = 0u; hw.ui[3] = 0u;
      }
      #pragma unroll
      for (int nt = 0; nt < 2; ++nt) {
        int nl = (wv * 2 + nt) * 16 + c;
        BF8 hf; hf.v = *(const bf16x8*)&hbuf[nl * HDIM + ((kc * 32 + g * 8) ^ cs)];
        acc2[nt] = __builtin_amdgcn_mfma_f32_16x16x32_bf16(hw.v, hf.v, acc2[nt], 0, 0, 0);
      }
    }
    if (g == 0) {
      #pragma unroll
      for (int nt = 0; nt < 2; ++nt) {
        int n = n0 + (wv * 2 + nt) * 16 + c;
        out[m * NPT + n]          = acc2[nt][0];
        out[SG_OFF + m * NPT + n] = expf(acc2[nt][1]);
      }
    }
  }
}

extern "C" void kernel_launch(void* const* d_in, const int* in_sizes, int n_in,
                              void* d_out, int out_size, void* d_ws, size_t ws_size,
                              hipStream_t stream) {
  const float* x   = (const float*)d_in[0];
  const float* W1  = (const float*)d_in[1];
  const float* b1  = (const float*)d_in[2];
  const float* Wh  = (const float*)d_in[3];
  const float* bh  = (const float*)d_in[4];
  const float* Wmu = (const float*)d_in[5];
  const float* bmu = (const float*)d_in[6];
  const float* Wsg = (const float*)d_in[7];
  const float* bsg = (const float*)d_in[8];
  unsigned short* ws = (unsigned short*)d_ws;
  (void)in_sizes; (void)n_in; (void)out_size; (void)ws_size;

  cvt_weights<<<(GTOT + 255) / 256, 256, 0, stream>>>(x, W1, Wh, Wmu, Wsg, ws);
  ens_mlp<<<12800, 256, 0, stream>>>(ws, b1, bh, bmu, bsg, (float*)d_out);
}

// Round 5
// 433.590 us; speedup vs baseline: 1.3147x; 1.3147x over previous
//
#include <hip/hip_runtime.h>

// BootstrapEnsemble: M=100 MLPs (16 -> 128 -> 4x(128x128) -> {mu, log sigma}),
// shared batch N=16384.
//  1) cvt_weights: one-shot fp32->bf16 (linear, row-major) of x/W1/Wh/Wmu/Wsig
//     into d_ws.
//  2) ens_mlp: fused MFMA MLP. Block = (model, 128-row n-chunk), 4 waves 2x2.
//     LDS = 32 KB h tile only. __launch_bounds__(256,3): 3 blocks/CU
//     (12 waves, 96 KB LDS), VGPR cap 170 -> no spill (R4's (256,4) cap of
//     128 split 64 arch + 64 AGPR and spilled: WRITE_SIZE 371 MB).
//     W fragments stream from L2-hot global per-kc. Swapped-operand
//     mfma_16x16x32_bf16; bias rides in the MFMA C operand.
//     LDS XOR swizzle: col ^= (row&15)<<3.

typedef float  f32x4  __attribute__((ext_vector_type(4)));
typedef __bf16 bf16x4 __attribute__((ext_vector_type(4)));
typedef __bf16 bf16x8 __attribute__((ext_vector_type(8)));

union BF8 { bf16x8 v; unsigned int ui[4]; };
union BF4 { bf16x4 v; uint2 u2; };

#define MODELS 100
#define NPT    16384
#define HDIM   128
#define SG_OFF (MODELS * NPT)

// d_ws layout (bf16 element offsets), all row-major / linear
#define XB_OFF   0                       // x:    16384 x 16
#define W1B_OFF  262144                  // W1:   100 x 128 x 16
#define WHB_OFF  466944                  // Wh:   100 x 4 x 128 x 128
#define WMU_OFF  7020544                 // Wmu:  100 x 128
#define WSG_OFF  7033344                 // Wsig: 100 x 128

#define GTOT 880768                      // total 8-elem groups

__global__ __launch_bounds__(256) void cvt_weights(
    const float* __restrict__ x,   const float* __restrict__ W1,
    const float* __restrict__ Wh,  const float* __restrict__ Wmu,
    const float* __restrict__ Wsg, unsigned short* __restrict__ ws)
{
  int gid = blockIdx.x * 256 + threadIdx.x;
  if (gid >= GTOT) return;
  const float* src;
  unsigned int dst;
  if (gid < 32768)       { src = x   + gid * 8;                 dst = XB_OFF  + gid * 8; }
  else if (gid < 58368)  { int q = gid - 32768;  src = W1  + q * 8;          dst = W1B_OFF + q * 8; }
  else if (gid < 877568) { int q = gid - 58368;  src = Wh  + (size_t)q * 8;  dst = WHB_OFF + q * 8; }
  else if (gid < 879168) { int q = gid - 877568; src = Wmu + q * 8;          dst = WMU_OFF + q * 8; }
  else                   { int q = gid - 879168; src = Wsg + q * 8;          dst = WSG_OFF + q * 8; }
  f32x4 a = *(const f32x4*)src;
  f32x4 b = *(const f32x4*)(src + 4);
  BF4 lo, hi;
  lo.v = __builtin_convertvector(a, bf16x4);
  hi.v = __builtin_convertvector(b, bf16x4);
  uint4 u; u.x = lo.u2.x; u.y = lo.u2.y; u.z = hi.u2.x; u.w = hi.u2.y;
  *(uint4*)&ws[dst] = u;
}

__global__ __launch_bounds__(256, 3) void ens_mlp(
    const unsigned short* __restrict__ ws,
    const float* __restrict__ b1,  const float* __restrict__ bh,
    const float* __restrict__ bmu, const float* __restrict__ bsg,
    float* __restrict__ out)
{
  __shared__ unsigned short hbuf[HDIM * HDIM]; // [n 0..127][h 0..127] bf16, swizzled

  // XCD-chunked bijective swizzle: 12800 blocks = 8 XCDs * 1600
  const int bid = blockIdx.x;
  const int swz = (bid & 7) * 1600 + (bid >> 3);
  const int m   = swz >> 7;            // model 0..99
  const int n0  = (swz & 127) << 7;    // 128-row chunk base

  const int t    = threadIdx.x;
  const int lane = t & 63;
  const int wv   = t >> 6;     // wave 0..3
  const int wk   = wv & 1;     // k_out half
  const int wn   = wv >> 1;    // n half
  const int c    = lane & 15;  // frag row (A: k_out, B: n) / D col (n)
  const int g    = lane >> 4;  // frag k-group / D row group
  const int cs   = c << 3;     // xor swizzle ((row&15)<<3)

  const f32x4 zf = {0.0f, 0.0f, 0.0f, 0.0f};

  f32x4 acc[4][4];   // [kt][nt]

  // ---------------- layer 1 (K=16 zero-padded to 32) -----------------------
  {
    const unsigned short* W1m = ws + W1B_OFF + m * (HDIM * 16);
    const unsigned short* xbp = ws + XB_OFF;
    BF8 a1[4], xb[4];
    #pragma unroll
    for (int kt = 0; kt < 4; ++kt) {
      if (g < 2) {
        a1[kt].v = *(const bf16x8*)&W1m[(wk * 64 + kt * 16 + c) * 16 + g * 8];
      } else {
        a1[kt].ui[0] = 0u; a1[kt].ui[1] = 0u; a1[kt].ui[2] = 0u; a1[kt].ui[3] = 0u;
      }
    }
    #pragma unroll
    for (int nt = 0; nt < 4; ++nt) {
      if (g < 2) {
        xb[nt].v = *(const bf16x8*)&xbp[(n0 + wn * 64 + nt * 16 + c) * 16 + g * 8];
      } else {
        xb[nt].ui[0] = 0u; xb[nt].ui[1] = 0u; xb[nt].ui[2] = 0u; xb[nt].ui[3] = 0u;
      }
    }
    f32x4 bs[4];
    #pragma unroll
    for (int kt = 0; kt < 4; ++kt)
      bs[kt] = *(const f32x4*)(b1 + m * HDIM + (wk * 4 + kt) * 16 + g * 4);

    #pragma unroll
    for (int kt = 0; kt < 4; ++kt)
      #pragma unroll
      for (int nt = 0; nt < 4; ++nt)
        acc[kt][nt] = __builtin_amdgcn_mfma_f32_16x16x32_bf16(a1[kt].v, xb[nt].v, bs[kt], 0, 0, 0);

    // epilogue: relu + cvt -> hbuf
    #pragma unroll
    for (int kt = 0; kt < 4; ++kt) {
      int col = ((wk * 4 + kt) * 16 + g * 4) ^ cs;
      #pragma unroll
      for (int nt = 0; nt < 4; ++nt) {
        int row = wn * 64 + nt * 16 + c;
        f32x4 v = __builtin_elementwise_max(acc[kt][nt], zf);
        BF4 b; b.v = __builtin_convertvector(v, bf16x4);
        *(uint2*)&hbuf[row * HDIM + col] = b.u2;
      }
    }
  }
  __syncthreads();

  // ---------------- 4 hidden layers ----------------------------------------
  for (int i = 0; i < 4; ++i) {
    const unsigned short* whm = ws + WHB_OFF + (size_t)(m * 4 + i) * (HDIM * HDIM);

    {
      f32x4 bs[4];
      #pragma unroll
      for (int kt = 0; kt < 4; ++kt)
        bs[kt] = *(const f32x4*)(bh + m * 512 + i * HDIM + (wk * 4 + kt) * 16 + g * 4);
      #pragma unroll
      for (int kt = 0; kt < 4; ++kt)
        #pragma unroll
        for (int nt = 0; nt < 4; ++nt)
          acc[kt][nt] = bs[kt];
    }

    #pragma unroll
    for (int kc = 0; kc < 4; ++kc) {
      BF8 af[4], bf[4];
      #pragma unroll
      for (int kt = 0; kt < 4; ++kt)
        af[kt].v = *(const bf16x8*)&whm[(wk * 64 + kt * 16 + c) * HDIM + kc * 32 + g * 8];
      #pragma unroll
      for (int nt = 0; nt < 4; ++nt)
        bf[nt].v = *(const bf16x8*)&hbuf[(wn * 64 + nt * 16 + c) * HDIM + ((kc * 32 + g * 8) ^ cs)];
      #pragma unroll
      for (int kt = 0; kt < 4; ++kt)
        #pragma unroll
        for (int nt = 0; nt < 4; ++nt)
          acc[kt][nt] = __builtin_amdgcn_mfma_f32_16x16x32_bf16(af[kt].v, bf[nt].v, acc[kt][nt], 0, 0, 0);
    }
    __syncthreads();   // all h reads of this layer done

    // epilogue: relu + cvt, write h in place
    #pragma unroll
    for (int kt = 0; kt < 4; ++kt) {
      int col = ((wk * 4 + kt) * 16 + g * 4) ^ cs;
      #pragma unroll
      for (int nt = 0; nt < 4; ++nt) {
        int row = wn * 64 + nt * 16 + c;
        f32x4 v = __builtin_elementwise_max(acc[kt][nt], zf);
        BF4 b; b.v = __builtin_convertvector(v, bf16x4);
        *(uint2*)&hbuf[row * HDIM + col] = b.u2;
      }
    }
    __syncthreads();
  }

  // ---------------- heads: mu (row 0) and log-sigma (row 1) ----------------
  {
    float bm  = bmu[m];
    float bsv = bsg[m];
    f32x4 acc2[2];
    #pragma unroll
    for (int nt = 0; nt < 2; ++nt) {
      acc2[nt] = zf;
      acc2[nt][0] = bm;
      acc2[nt][1] = bsv;
    }
    #pragma unroll
    for (int kc = 0; kc < 4; ++kc) {
      BF8 hw;
      if (c < 2) {
        const unsigned short* wp = ws + (c == 0 ? WMU_OFF : WSG_OFF) + m * HDIM + kc * 32 + g * 8;
        hw.v = *(const bf16x8*)wp;
      } else {
        hw.ui[0] = 0u; hw.ui[1] = 0u; hw.ui[2] = 0u; hw.ui[3] = 0u;
      }
      #pragma unroll
      for (int nt = 0; nt < 2; ++nt) {
        int nl = (wv * 2 + nt) * 16 + c;
        BF8 hf; hf.v = *(const bf16x8*)&hbuf[nl * HDIM + ((kc * 32 + g * 8) ^ cs)];
        acc2[nt] = __builtin_amdgcn_mfma_f32_16x16x32_bf16(hw.v, hf.v, acc2[nt], 0, 0, 0);
      }
    }
    if (g == 0) {
      #pragma unroll
      for (int nt = 0; nt < 2; ++nt) {
        int n = n0 + (wv * 2 + nt) * 16 + c;
        out[m * NPT + n]          = acc2[nt][0];
        out[SG_OFF + m * NPT + n] = expf(acc2[nt][1]);
      }
    }
  }
}

extern "C" void kernel_launch(void* const* d_in, const int* in_sizes, int n_in,
                              void* d_out, int out_size, void* d_ws, size_t ws_size,
                              hipStream_t stream) {
  const float* x   = (const float*)d_in[0];
  const float* W1  = (const float*)d_in[1];
  const float* b1  = (const float*)d_in[2];
  const float* Wh  = (const float*)d_in[3];
  const float* bh  = (const float*)d_in[4];
  const float* Wmu = (const float*)d_in[5];
  const float* bmu = (const float*)d_in[6];
  const float* Wsg = (const float*)d_in[7];
  const float* bsg = (const float*)d_in[8];
  unsigned short* ws = (unsigned short*)d_ws;
  (void)in_sizes; (void)n_in; (void)out_size; (void)ws_size;

  cvt_weights<<<(GTOT + 255) / 256, 256, 0, stream>>>(x, W1, Wh, Wmu, Wsg, ws);
  ens_mlp<<<12800, 256, 0, stream>>>(ws, b1, bh, bmu, bsg, (float*)d_out);
}